// Round 6
// baseline (93.624 us; speedup 1.0000x reference)
//
#include <hip/hip_runtime.h>

#define NBOXES 4096
#define MAX_BS 128
#define NPTS (NBOXES * MAX_BS)
#define INV4PI 0.07957747154594767f
#define RSQRT2 0.70710678118654752f

// ---- Pass 1: pack {x, y, z, h = 0.5*|x|^2} per point into d_ws ----
__global__ __launch_bounds__(256) void prep_kernel(
    const float* __restrict__ XX, float4* __restrict__ pk)
{
    const int i = blockIdx.x * 256 + threadIdx.x;   // < NPTS
    const float x = XX[3 * i + 0];
    const float y = XX[3 * i + 1];
    const float z = XX[3 * i + 2];
    const float h = 0.5f * fmaf(x, x, fmaf(y, y, z * z));
    pk[i] = make_float4(x, y, z, h);
}

// Expansion inner loop: r^2 = 2*(h_u + h_q - dot); 1/r = rsq(g)/sqrt(2).
// 6 VALU per row per source point (3 fma w/ free neg + add + rsq + fma).
template<int NR>
__device__ __forceinline__ void sweep_exp(
    const float4* __restrict__ pq, const float* __restrict__ qv, int bs_q,
    const float4* A, float* acc)
{
    int j = 0;
    for (; j + 8 <= bs_q; j += 8) {
        float4 s[8]; float wq[8];
#pragma unroll
        for (int c = 0; c < 8; ++c) { s[c] = pq[j + c]; wq[c] = qv[j + c]; }
#pragma unroll
        for (int c = 0; c < 8; ++c) {
#pragma unroll
            for (int r = 0; r < NR; ++r) {
                float g = fmaf(-A[r].x, s[c].x, A[r].w);
                g = fmaf(-A[r].y, s[c].y, g);
                g = fmaf(-A[r].z, s[c].z, g);
                g += s[c].w;
                acc[r] = fmaf(wq[c], __builtin_amdgcn_rsqf(g), acc[r]);
            }
        }
    }
    for (; j < bs_q; ++j) {
        const float4 s = pq[j]; const float wq = qv[j];
#pragma unroll
        for (int r = 0; r < NR; ++r) {
            float g = fmaf(-A[r].x, s.x, A[r].w);
            g = fmaf(-A[r].y, s.y, g);
            g = fmaf(-A[r].z, s.z, g);
            g += s.w;
            acc[r] = fmaf(wq, __builtin_amdgcn_rsqf(g), acc[r]);
        }
    }
}

// Self-pair (u==q, ~2/8192): exact direct form so self-interaction r2==0.
template<int NR>
__device__ __forceinline__ void sweep_self(
    const float4* __restrict__ pq, const float* __restrict__ qv, int bs_q,
    const float4* A, float* acc)
{
    for (int j = 0; j < bs_q; ++j) {
        const float4 s = pq[j]; const float wq = qv[j];
#pragma unroll
        for (int r = 0; r < NR; ++r) {
            const float dx = A[r].x - s.x;
            const float dy = A[r].y - s.y;
            const float dz = A[r].z - s.z;
            const float r2 = fmaf(dx, dx, fmaf(dy, dy, dz * dz));
            float rv = __builtin_amdgcn_rsqf(r2);
            rv = (r2 > 0.0f) ? rv : 0.0f;
            acc[r] = fmaf(wq, rv, acc[r]);
        }
    }
}

// ---- Pass 2: one WAVE per pair; lane t owns rows t and t+64 (row 1 gated
// on wave-uniform bs_u>64). No LDS, no barrier: source box read through the
// scalar pipe (uniform addresses). Block = 256 = 4 independent waves.
__global__ __launch_bounds__(256) void fmm_kernel(
    const float*  __restrict__ q_vec,    // [NBOXES][MAX_BS]
    const float4* __restrict__ pk,       // packed points (d_ws)
    const int*    __restrict__ bs_list,  // [NBOXES]
    const int2*   __restrict__ uq_boxes, // [NPAIRS]
    int npairs,
    float*        __restrict__ out)      // [NBOXES][MAX_BS]
{
    const int w = threadIdx.x >> 6;      // wave in block
    const int t = threadIdx.x & 63;      // lane
    const int p = blockIdx.x * 4 + w;    // pair id
    if (p >= npairs) return;

    const int2 uq = uq_boxes[p];
    const int u = __builtin_amdgcn_readfirstlane(uq.x);
    const int q = __builtin_amdgcn_readfirstlane(uq.y);
    const int bs_u = bs_list[u];
    const int bs_q = bs_list[q];
    if (bs_u == 0 || bs_q == 0) return;

    const float4* __restrict__ pq = pk + (size_t)q * MAX_BS;
    const float*  __restrict__ qv = q_vec + (size_t)q * MAX_BS;

    float4 A[2];
    A[0] = pk[(size_t)u * MAX_BS + t];
    const bool two = (bs_u > 64);        // wave-uniform
    if (two) A[1] = pk[(size_t)u * MAX_BS + t + 64];

    float acc[2] = {0.0f, 0.0f};
    float scale;
    if (u != q) {
        if (two) sweep_exp<2>(pq, qv, bs_q, A, acc);
        else     sweep_exp<1>(pq, qv, bs_q, A, acc);
        scale = INV4PI * RSQRT2;         // fold rsq(2g) = rsq(g)/sqrt(2)
    } else {
        if (two) sweep_self<2>(pq, qv, bs_q, A, acc);
        else     sweep_self<1>(pq, qv, bs_q, A, acc);
        scale = INV4PI;
    }

    float* orow = out + (size_t)u * MAX_BS;
    if (t < bs_u)               atomicAdd(orow + t,      acc[0] * scale);
    if (two && t + 64 < bs_u)   atomicAdd(orow + t + 64, acc[1] * scale);
}

extern "C" void kernel_launch(void* const* d_in, const int* in_sizes, int n_in,
                              void* d_out, int out_size, void* d_ws, size_t ws_size,
                              hipStream_t stream) {
    const float* q_vec    = (const float*)d_in[0];
    const float* XX_list  = (const float*)d_in[1];
    const int*   bs_list  = (const int*)d_in[2];
    const int2*  uq_boxes = (const int2*)d_in[3];
    float* out = (float*)d_out;

    const int npairs = in_sizes[3] / 2;             // 8192

    float4* pk = (float4*)d_ws;                     // 8 MB packed points

    // Atomic accumulation needs a zeroed output (harness poisons with 0xAA).
    hipMemsetAsync(d_out, 0, (size_t)out_size * sizeof(float), stream);

    prep_kernel<<<NPTS / 256, 256, 0, stream>>>(XX_list, pk);

    fmm_kernel<<<(npairs + 3) / 4, 256, 0, stream>>>(
        q_vec, pk, bs_list, uq_boxes, npairs, out);
}

// Round 7
// 92.000 us; speedup vs baseline: 1.0177x; 1.0177x over previous
//
#include <hip/hip_runtime.h>

#define MAX_BS 128
#define INV4PI 0.07957747154594767f

// Block = pair (u,q), 128 threads = 2 waves.
// Wave h sweeps source-half h of box q; lane t owns target rows 2t, 2t+1.
// Source stream read through the scalar pipe (uniform addresses); no LDS,
// no barrier. Halves combine via atomicAdd (out pre-zeroed).
__global__ __launch_bounds__(128) void fmm_split_kernel(
    const float* __restrict__ q_vec,    // [NBOXES][MAX_BS]
    const float* __restrict__ XX,       // [NBOXES][MAX_BS][3]
    const int*   __restrict__ bs_list,  // [NBOXES]
    const int2*  __restrict__ uq_boxes, // [NPAIRS]
    float*       __restrict__ out)      // [NBOXES][MAX_BS]
{
    const int p = blockIdx.x;
    const int h = threadIdx.x >> 6;     // source half (wave id)
    const int t = threadIdx.x & 63;     // lane

    const int2 uq = uq_boxes[p];
    const int u = __builtin_amdgcn_readfirstlane(uq.x);
    const int q = __builtin_amdgcn_readfirstlane(uq.y);
    const int bs_u = bs_list[u];
    const int bs_q = bs_list[q];
    if (bs_u == 0) return;

    // This wave's source range [j0, j1).
    const int hs = (bs_q + 1) >> 1;
    const int j0 = h * hs;
    const int j1 = (bs_q < j0 + hs) ? bs_q : (j0 + hs);
    if (j0 >= j1) return;

    // Own target rows 2t and 2t+1 (24 contiguous bytes).
    const int r0 = 2 * t;
    const float* __restrict__ Xu = XX + (size_t)u * (MAX_BS * 3) + 6 * t;
    const float x0 = Xu[0], y0 = Xu[1], z0 = Xu[2];
    const float x1 = Xu[3], y1 = Xu[4], z1 = Xu[5];

    // Uniform source pointers -> scalar-pipe loads in the loop.
    const float* __restrict__ Xq = XX + (size_t)q * (MAX_BS * 3);
    const float* __restrict__ qv = q_vec + (size_t)q * MAX_BS;

    float acc0 = 0.0f, acc1 = 0.0f;

    if (u != q) {
        // Distinct boxes: r2 > 0 always (continuous random coords).
        int j = j0;
        for (; j + 8 <= j1; j += 8) {
            float sx[8], sy[8], sz[8], w[8];
#pragma unroll
            for (int c = 0; c < 8; ++c) {
                sx[c] = Xq[3 * (j + c) + 0];
                sy[c] = Xq[3 * (j + c) + 1];
                sz[c] = Xq[3 * (j + c) + 2];
                w[c]  = qv[j + c];
            }
#pragma unroll
            for (int c = 0; c < 8; ++c) {
                const float dx0 = x0 - sx[c], dy0 = y0 - sy[c], dz0 = z0 - sz[c];
                const float r20 = fmaf(dx0, dx0, fmaf(dy0, dy0, dz0 * dz0));
                acc0 = fmaf(w[c], __builtin_amdgcn_rsqf(r20), acc0);
                const float dx1 = x1 - sx[c], dy1 = y1 - sy[c], dz1 = z1 - sz[c];
                const float r21 = fmaf(dx1, dx1, fmaf(dy1, dy1, dz1 * dz1));
                acc1 = fmaf(w[c], __builtin_amdgcn_rsqf(r21), acc1);
            }
        }
        for (; j < j1; ++j) {
            const float sx = Xq[3 * j + 0], sy = Xq[3 * j + 1], sz = Xq[3 * j + 2];
            const float w  = qv[j];
            const float dx0 = x0 - sx, dy0 = y0 - sy, dz0 = z0 - sz;
            const float r20 = fmaf(dx0, dx0, fmaf(dy0, dy0, dz0 * dz0));
            acc0 = fmaf(w, __builtin_amdgcn_rsqf(r20), acc0);
            const float dx1 = x1 - sx, dy1 = y1 - sy, dz1 = z1 - sz;
            const float r21 = fmaf(dx1, dx1, fmaf(dy1, dy1, dz1 * dz1));
            acc1 = fmaf(w, __builtin_amdgcn_rsqf(r21), acc1);
        }
    } else {
        // Self pair (~2/8192, block-uniform): guard exact self-interaction.
        for (int j = j0; j < j1; ++j) {
            const float sx = Xq[3 * j + 0], sy = Xq[3 * j + 1], sz = Xq[3 * j + 2];
            const float w  = qv[j];
            const float dx0 = x0 - sx, dy0 = y0 - sy, dz0 = z0 - sz;
            const float r20 = fmaf(dx0, dx0, fmaf(dy0, dy0, dz0 * dz0));
            float rv0 = __builtin_amdgcn_rsqf(r20);
            rv0 = (r20 > 0.0f) ? rv0 : 0.0f;
            acc0 = fmaf(w, rv0, acc0);
            const float dx1 = x1 - sx, dy1 = y1 - sy, dz1 = z1 - sz;
            const float r21 = fmaf(dx1, dx1, fmaf(dy1, dy1, dz1 * dz1));
            float rv1 = __builtin_amdgcn_rsqf(r21);
            rv1 = (r21 > 0.0f) ? rv1 : 0.0f;
            acc1 = fmaf(w, rv1, acc1);
        }
    }

    float* orow = out + (size_t)u * MAX_BS + r0;
    if (r0     < bs_u) atomicAdd(orow + 0, acc0 * INV4PI);
    if (r0 + 1 < bs_u) atomicAdd(orow + 1, acc1 * INV4PI);
}

extern "C" void kernel_launch(void* const* d_in, const int* in_sizes, int n_in,
                              void* d_out, int out_size, void* d_ws, size_t ws_size,
                              hipStream_t stream) {
    const float* q_vec    = (const float*)d_in[0];
    const float* XX_list  = (const float*)d_in[1];
    const int*   bs_list  = (const int*)d_in[2];
    const int2*  uq_boxes = (const int2*)d_in[3];
    float* out = (float*)d_out;

    const int npairs = in_sizes[3] / 2;   // 8192

    // Atomic accumulation needs a zeroed output (harness poisons with 0xAA).
    hipMemsetAsync(d_out, 0, (size_t)out_size * sizeof(float), stream);

    fmm_split_kernel<<<npairs, 128, 0, stream>>>(
        q_vec, XX_list, bs_list, uq_boxes, out);
}

// Round 8
// 86.930 us; speedup vs baseline: 1.0770x; 1.0583x over previous
//
#include <hip/hip_runtime.h>

#define NBOXES 4096
#define MAX_BS 128
#define NPTS (NBOXES * MAX_BS)
#define INV4PI 0.07957747154594767f

typedef float v2f __attribute__((ext_vector_type(2)));

// ---- Pass 1: pair-interleaved SoA repack into d_ws ----
// Group k of box b (sources j=2k, 2k+1) = 8 dwords:
//   {x2k, x2k+1, y2k, y2k+1, z2k, z2k+1, w2k, w2k+1}
// with w = (j < bs) ? qv[j]*INV4PI : 0  (col-mask + scale pre-folded).
// One group = one s_load_dwordx8 in the main loop; halves feed v_pk_* ops.
__global__ __launch_bounds__(256) void prep_kernel(
    const float* __restrict__ XX, const float* __restrict__ q_vec,
    const int* __restrict__ bs_list, float4* __restrict__ pk)
{
    const int g = blockIdx.x * 256 + threadIdx.x;  // group id < NPTS/2
    const int b = g >> 6;                          // box (64 groups/box)
    const int j = (g & 63) * 2;                    // first source of group
    const float* X = XX + (size_t)b * (MAX_BS * 3) + 3 * j;
    const float x0 = X[0], y0 = X[1], z0 = X[2];
    const float x1 = X[3], y1 = X[4], z1 = X[5];
    const int bs = bs_list[b];
    const float* qv = q_vec + (size_t)b * MAX_BS + j;
    const float w0 = (j     < bs) ? qv[0] * INV4PI : 0.0f;
    const float w1 = (j + 1 < bs) ? qv[1] * INV4PI : 0.0f;
    pk[2 * g + 0] = make_float4(x0, x1, y0, y1);
    pk[2 * g + 1] = make_float4(z0, z1, w0, w1);
}

// ---- Pass 2: R5 structure + packed-FP32 inner loop ----
// One block per pair, 128 threads, lane t = target row t (exact exec mask).
// Source stream: uniform addresses -> scalar pipe; 2 sources/iter as v2f
// (v_pk_fma_f32 etc.), rsq per component. No LDS, no barrier.
__global__ __launch_bounds__(128) void fmm_packed_kernel(
    const float* __restrict__ XX,       // [NBOXES][MAX_BS][3]
    const int*   __restrict__ bs_list,  // [NBOXES]
    const int2*  __restrict__ uq_boxes, // [NPAIRS]
    const v2f*   __restrict__ pk,       // packed groups (d_ws)
    float*       __restrict__ out)      // [NBOXES][MAX_BS]
{
    const int p = blockIdx.x;
    const int t = threadIdx.x;

    const int2 uq = uq_boxes[p];
    const int u = __builtin_amdgcn_readfirstlane(uq.x);
    const int q = __builtin_amdgcn_readfirstlane(uq.y);
    const int bs_u = bs_list[u];
    if (t >= bs_u) return;              // dead rows (often wave 1) exit fast
    const int bs_q = bs_list[q];
    const int ng = (bs_q + 1) >> 1;     // groups to sweep (w=0 pads the tail)

    // Own target point.
    const float* __restrict__ Xu = XX + (size_t)u * (MAX_BS * 3) + 3 * t;
    const float xu = Xu[0], yu = Xu[1], zu = Xu[2];

    // Uniform source group stream: 4 v2f per group, contiguous 32 B.
    const v2f* __restrict__ pq = pk + (size_t)q * (MAX_BS * 2);

    float acc = 0.0f;
    if (u != q) {
        const v2f xup = {xu, xu}, yup = {yu, yu}, zup = {zu, zu};
        v2f accp = {0.0f, 0.0f};
#pragma unroll 4
        for (int k = 0; k < ng; ++k) {
            const v2f sx = pq[4 * k + 0];
            const v2f sy = pq[4 * k + 1];
            const v2f sz = pq[4 * k + 2];
            const v2f sw = pq[4 * k + 3];
            const v2f dx = xup - sx;
            const v2f dy = yup - sy;
            const v2f dz = zup - sz;
            v2f r2 = dx * dx;
            r2 = __builtin_elementwise_fma(dy, dy, r2);
            r2 = __builtin_elementwise_fma(dz, dz, r2);
            v2f rv;
            rv.x = __builtin_amdgcn_rsqf(r2.x);
            rv.y = __builtin_amdgcn_rsqf(r2.y);
            accp = __builtin_elementwise_fma(sw, rv, accp);
        }
        acc = accp.x + accp.y;
    } else {
        // Self pair (~2/8192, block-uniform): scalar path, exact r2==0 guard.
        for (int j = 0; j < bs_q; ++j) {
            const float* g = (const float*)(pq + 4 * (j >> 1));
            const int o = j & 1;
            const float sx = g[0 + o], sy = g[2 + o];
            const float sz = g[4 + o], sw = g[6 + o];
            const float dx = xu - sx, dy = yu - sy, dz = zu - sz;
            const float r2 = fmaf(dx, dx, fmaf(dy, dy, dz * dz));
            float rv = __builtin_amdgcn_rsqf(r2);
            rv = (r2 > 0.0f) ? rv : 0.0f;
            acc = fmaf(sw, rv, acc);
        }
    }

    // INV4PI + col mask already folded into w during prep.
    atomicAdd(out + (size_t)u * MAX_BS + t, acc);
}

extern "C" void kernel_launch(void* const* d_in, const int* in_sizes, int n_in,
                              void* d_out, int out_size, void* d_ws, size_t ws_size,
                              hipStream_t stream) {
    const float* q_vec    = (const float*)d_in[0];
    const float* XX_list  = (const float*)d_in[1];
    const int*   bs_list  = (const int*)d_in[2];
    const int2*  uq_boxes = (const int2*)d_in[3];
    float* out = (float*)d_out;

    const int npairs = in_sizes[3] / 2;   // 8192

    float4* pk = (float4*)d_ws;           // 8 MB packed groups

    // Atomic accumulation needs a zeroed output (harness poisons with 0xAA).
    hipMemsetAsync(d_out, 0, (size_t)out_size * sizeof(float), stream);

    prep_kernel<<<(NPTS / 2) / 256, 256, 0, stream>>>(
        XX_list, q_vec, bs_list, pk);

    fmm_packed_kernel<<<npairs, 128, 0, stream>>>(
        XX_list, bs_list, uq_boxes, (const v2f*)pk, out);
}